// Round 4
// baseline (107.246 us; speedup 1.0000x reference)
//
#include <hip/hip_runtime.h>
#include <hip/hip_cooperative_groups.h>

namespace cg = cooperative_groups;

#define G_ 19
#define A_ 5
#define C_ 20
#define BS_ 16
#define N_ (G_*G_*A_)        // 1805
#define CHK 8                // chunks (blocks) per batch
#define NSTR 2048            // per-batch stride in dense arrays
#define NBLK (BS_*CHK)       // 128 blocks
#define EPSF 1e-8f

// pairwise tiling
#define JCAP 128
#define IPT 2
#define ITILE (256*IPT)                       // 512
#define JT ((N_ + JCAP - 1)/JCAP)             // 15
#define IT ((N_ + ITILE - 1)/ITILE)           // 4

// ws byte offsets (all 16B-aligned)
#define OFF_P1  0                              // float[128]
#define OFF_P2  (OFF_P1 + NBLK*4)              // float[128]
#define OFF_CP  (OFF_P2 + NBLK*4)              // u32[128]
#define OFF_CN  (OFF_CP + NBLK*4)              // u32[128]
#define OFF_TP  (OFF_CN + NBLK*4)              // u32[16]
#define OFF_TN  (OFF_TP + BS_*4)               // u32[16]
#define OFF_PLB (OFF_TN + BS_*4)               // float4[128][256]
#define OFF_PLA (OFF_PLB + NBLK*256*16)        // float [128][256]
#define OFF_NLB (OFF_PLA + NBLK*256*4)         // float4[128][256]
#define OFF_NLV (OFF_NLB + NBLK*256*16)        // float [128][256]
#define OFF_DPB (OFF_NLV + NBLK*256*4)         // float4[16][2048]
#define OFF_DPA (OFF_DPB + BS_*NSTR*16)        // float [16][2048]
#define OFF_DNB (OFF_DPA + BS_*NSTR*4)         // float4[16][2048]
#define OFF_DNV (OFF_DNB + BS_*NSTR*16)        // float [16][2048]
#define OFF_FLG (OFF_DNV + BS_*NSTR*4)         // u32  [16][2048]

__device__ __forceinline__ float sigmoidf_(float x) {
    return 1.0f / (1.0f + __expf(-x));
}

__device__ __forceinline__ float block_sum(float v, float* red, int tid) {
    for (int off = 32; off; off >>= 1) v += __shfl_down(v, off);
    int wid = tid >> 6, lane = tid & 63;
    if (lane == 0) red[wid] = v;
    __syncthreads();
    float s = red[0] + red[1] + red[2] + red[3];
    __syncthreads();          // allow red[] reuse afterwards
    return s;
}

__global__ __launch_bounds__(256) void yolo_fused(
    const float* __restrict__ pred, const float* __restrict__ gt,
    const float* __restrict__ anch, const int* __restrict__ epoch_p,
    float* __restrict__ out, char* __restrict__ ws)
{
    cg::grid_group grid = cg::this_grid();

    float*    partial1 = (float*)(ws + OFF_P1);
    float*    partial2 = (float*)(ws + OFF_P2);
    unsigned* cntP  = (unsigned*)(ws + OFF_CP);
    unsigned* cntN  = (unsigned*)(ws + OFF_CN);
    unsigned* totP  = (unsigned*)(ws + OFF_TP);
    unsigned* totN  = (unsigned*)(ws + OFF_TN);
    float4*   plbox = (float4*)(ws + OFF_PLB);
    float*    plab  = (float*) (ws + OFF_PLA);
    float4*   nlbox = (float4*)(ws + OFF_NLB);
    float*    nlval = (float*) (ws + OFF_NLV);
    float4*   dpbox = (float4*)(ws + OFF_DPB);
    float*    dpab  = (float*) (ws + OFF_DPA);
    float4*   dnbox = (float4*)(ws + OFF_DNB);
    float*    dnval = (float*) (ws + OFF_DNV);
    unsigned* flags = (unsigned*)(ws + OFF_FLG);

    __shared__ __align__(16) float smem[256*50];   // 51.2 KB
    __shared__ float red[4];
    __shared__ int wpo[4], wno[4];

    const int tid  = threadIdx.x;
    const int lane = tid & 63, wid = tid >> 6;
    const int b    = blockIdx.y;
    const int ch   = blockIdx.x;
    const int blin = b * CHK + ch;

    // ======== phase 1: elementwise losses + block-local compaction ========
    float* sp = smem;
    float* sg = smem + 256*25;
    {
        int n0   = ch * 256;
        int rows = min(256, N_ - n0);
        int ndw  = rows * 25;
        const float* srcP = pred + ((size_t)b*N_ + n0)*25;
        const float* srcG = gt   + ((size_t)b*N_ + n0)*25;
        for (int d = tid; d < ndw; d += 256) { sp[d] = srcP[d]; sg[d] = srcG[d]; }
        __syncthreads();

        int n = n0 + tid;
        bool valid = tid < rows;
        const float* P = sp + tid*25;
        const float* T = sg + tid*25;
        float local = 0.f;

        bool pos = false;
        float gx1=0, gy1=0, gx2=0, gy2=0, area_g=0;
        float px1=0, py1=0, px2=0, py2=0, pconf=0;

        if (valid) {
            flags[b*NSTR + n] = 0u;
            int a  = n % A_;
            int g2 = (n / A_) % G_;
            int g1 = n / (A_ * G_);
            float px = P[0], py = P[1], pw = P[2], ph = P[3], po = P[4];
            float gx = T[0], gy = T[1], gw = T[2], gh = T[3], go = T[4];
            float aw = anch[a*2+0], ah = anch[a*2+1];

            float sx  = sigmoidf_(px), sy = sigmoidf_(py);
            float pbw = __expf(pw) * aw, pbh = __expf(ph) * ah;
            float gbw = __expf(gw) * aw, gbh = __expf(gh) * ah;

            float cxp = sx + (float)g2, cyp = sy + (float)g1;
            float hwp = pbw * (0.5f * G_), hhp = pbh * (0.5f * G_);
            px1 = cxp - hwp; py1 = cyp - hhp; px2 = cxp + hwp; py2 = cyp + hhp;

            float cxg = gx + (float)g2, cyg = gy + (float)g1;
            float hwg = gbw * (0.5f * G_), hhg = gbh * (0.5f * G_);
            gx1 = cxg - hwg; gy1 = cyg - hhg; gx2 = cxg + hwg; gy2 = cyg + hhg;

            pconf = sigmoidf_(po);
            float area_p = fmaxf(px2 - px1, 0.f) * fmaxf(py2 - py1, 0.f);
            area_g = fmaxf(gx2 - gx1, 0.f) * fmaxf(gy2 - gy1, 0.f);

            if (*epoch_p < 12) {
                local += 0.01f * (px*px + py*py + pw*pw + ph*ph);
            }
            pos = go > 0.5f;
            if (pos) {
                float d0 = gx - sx, d1 = gy - sy, d2 = gw - pw, d3 = gh - ph;
                local += 5.0f * (d0*d0 + d1*d1 + d2*d2 + d3*d3);
                float ix1 = fmaxf(px1, gx1), iy1 = fmaxf(py1, gy1);
                float ix2 = fminf(px2, gx2), iy2 = fminf(py2, gy2);
                float iw = fmaxf(ix2 - ix1, 0.f), ih = fmaxf(iy2 - iy1, 0.f);
                float inter = iw * ih;
                float iou = inter / (area_p + area_g - inter + EPSF);
                float dc = iou - pconf;
                local += dc * dc;
                float cl[C_];
                float m = -1e30f;
                #pragma unroll
                for (int c = 0; c < C_; c++) { cl[c] = P[5+c]; m = fmaxf(m, cl[c]); }
                float s = 0.f;
                #pragma unroll
                for (int c = 0; c < C_; c++) { cl[c] = __expf(cl[c] - m); s += cl[c]; }
                float inv = 1.0f / s;
                float acc = 0.f;
                #pragma unroll
                for (int c = 0; c < C_; c++) { float d = T[5+c] - cl[c]*inv; acc += d*d; }
                local += acc;
            }
            local *= (1.0f / BS_);
        }

        // deterministic block-local compaction (no atomics)
        bool isPos = valid && pos;
        bool isNeg = valid && !pos;
        unsigned long long mp = __ballot(isPos);
        unsigned long long mn = __ballot(isNeg);
        unsigned long long ltm = (1ull << lane) - 1ull;
        int ppre = __popcll(mp & ltm);
        int npre = __popcll(mn & ltm);
        if (lane == 0) { wpo[wid] = __popcll(mp); wno[wid] = __popcll(mn); }
        __syncthreads();
        int pexc = 0, nexc = 0, tp = 0, tn = 0;
        #pragma unroll
        for (int w = 0; w < 4; w++) {
            if (w < wid) { pexc += wpo[w]; nexc += wno[w]; }
            tp += wpo[w]; tn += wno[w];
        }
        if (isPos) {
            int k = blin*256 + pexc + ppre;
            plbox[k] = make_float4(gx1, gy1, gx2, gy2);
            plab[k]  = area_g;
        } else if (isNeg) {
            int k = blin*256 + nexc + npre;
            nlbox[k] = make_float4(px1, py1, px2, py2);
            nlval[k] = (0.5f / BS_) * pconf * pconf;
        }
        if (tid == 0) { cntP[blin] = (unsigned)tp; cntN[blin] = (unsigned)tn; }

        float bsum = block_sum(local, red, tid);
        if (tid == 0) partial1[blin] = bsum;
    }

    grid.sync();

    // ======== phase 2: densify per-batch lists ========
    {
        int myP = (int)cntP[blin], myN = (int)cntN[blin];
        int baseP = 0, baseN = 0, tp = 0, tn = 0;
        #pragma unroll
        for (int w = 0; w < CHK; w++) {
            int cp = (int)cntP[b*CHK + w];
            int cn = (int)cntN[b*CHK + w];
            if (w < ch) { baseP += cp; baseN += cn; }
            tp += cp; tn += cn;
        }
        for (int k = tid; k < myP; k += 256) {
            dpbox[b*NSTR + baseP + k] = plbox[blin*256 + k];
            dpab [b*NSTR + baseP + k] = plab [blin*256 + k];
        }
        for (int k = tid; k < myN; k += 256) {
            dnbox[b*NSTR + baseN + k] = nlbox[blin*256 + k];
            dnval[b*NSTR + baseN + k] = nlval[blin*256 + k];
        }
        if (ch == 0 && tid == 0) { totP[b] = (unsigned)tp; totN[b] = (unsigned)tn; }
    }

    grid.sync();

    // ======== phase 3: pairwise max-IoU predicate ========
    {
        float4* sbox = (float4*)smem;            // 128 * 16B
        float*  sb06 = smem + 512;               // 128 floats: -0.6*area_b
        for (int t = blin; t < BS_*IT*JT; t += NBLK) {
            int tb  = t / (IT*JT);
            int r   = t - tb*(IT*JT);
            int icx = r / JT;
            int jcx = r - icx*JT;
            int npos = (int)totP[tb], nn = (int)totN[tb];
            int jst  = jcx * JCAP;
            int jlen = min(npos - jst, JCAP);
            int ist  = icx * ITILE;
            if (jlen <= 0 || ist >= nn) continue;    // block-uniform
            __syncthreads();                          // protect LDS reuse
            if (tid < jlen) {
                sbox[tid] = dpbox[tb*NSTR + jst + tid];
                sb06[tid] = -0.6f * dpab[tb*NSTR + jst + tid];
            }
            __syncthreads();

            int i0 = ist + tid, i1 = i0 + 256;
            bool v0 = i0 < nn, v1 = i1 < nn;
            float4 p0 = v0 ? dnbox[tb*NSTR + i0] : make_float4(0,0,0,0);
            float4 p1 = v1 ? dnbox[tb*NSTR + i1] : make_float4(0,0,0,0);
            float c0 = (p0.z - p0.x) * (p0.w - p0.y) + EPSF;
            float c1 = (p1.z - p1.x) * (p1.w - p1.y) + EPSF;

            float md0 = -1e30f, md1 = -1e30f;
            for (int j = 0; j < jlen; j++) {
                float4 g = sbox[j];
                float tt = sb06[j];
                float ax0 = fmaxf(p0.x, g.x), ay0 = fmaxf(p0.y, g.y);
                float bx0 = fminf(p0.z, g.z), by0 = fminf(p0.w, g.w);
                float in0 = fmaxf(bx0 - ax0, 0.f) * fmaxf(by0 - ay0, 0.f);
                md0 = fmaxf(md0, fmaf(1.6f, in0, tt));
                float ax1 = fmaxf(p1.x, g.x), ay1 = fmaxf(p1.y, g.y);
                float bx1 = fminf(p1.z, g.z), by1 = fminf(p1.w, g.w);
                float in1 = fmaxf(bx1 - ax1, 0.f) * fmaxf(by1 - ay1, 0.f);
                md1 = fmaxf(md1, fmaf(1.6f, in1, tt));
            }
            // iou >= 0.6  <=>  1.6*inter - 0.6*area_b >= 0.6*(area_a + eps)
            if (v0 && md0 >= 0.6f * c0) flags[tb*NSTR + i0] = 1u;  // same-value race: benign
            if (v1 && md1 >= 0.6f * c1) flags[tb*NSTR + i1] = 1u;
        }
    }

    grid.sync();

    // ======== phase 4: noobj partial sums ========
    {
        int nn = (int)totN[b];
        int i = ch*256 + tid;
        float v = 0.f;
        if (i < nn && flags[b*NSTR + i] == 0u) v = dnval[b*NSTR + i];
        float s = block_sum(v, red, tid);
        if (tid == 0) partial2[blin] = s;
    }

    grid.sync();

    // ======== phase 5: final reduction ========
    if (blin == 0) {
        float v = (tid < NBLK) ? (partial1[tid] + partial2[tid]) : 0.f;
        float s = block_sum(v, red, tid);
        if (tid == 0) out[0] = s;
    }
}

extern "C" void kernel_launch(void* const* d_in, const int* in_sizes, int n_in,
                              void* d_out, int out_size, void* d_ws, size_t ws_size,
                              hipStream_t stream) {
    const float* pred  = (const float*)d_in[0];
    const float* gt_   = (const float*)d_in[1];
    const float* anch  = (const float*)d_in[2];
    const int*   epoch = (const int*)d_in[3];
    float* out = (float*)d_out;
    char*  ws  = (char*)d_ws;

    void* args[] = { (void*)&pred, (void*)&gt_, (void*)&anch,
                     (void*)&epoch, (void*)&out, (void*)&ws };
    dim3 grid(CHK, BS_), block(256);
    hipLaunchCooperativeKernel(reinterpret_cast<void*>(yolo_fused),
                               grid, block, args, 0, stream);
}

// Round 5
// 50.695 us; speedup vs baseline: 2.1155x; 2.1155x over previous
//
#include <hip/hip_runtime.h>

#define G_ 19
#define A_ 5
#define C_ 20
#define BS_ 16
#define N_ (G_*G_*A_)        // 1805
#define CHK 8                // segments (blocks) per batch
#define SEG 256              // slots per segment
#define NBLK (BS_*CHK)       // 128
#define EPSF 1e-8f

// ws byte offsets (16B-aligned blocks)
#define OFF_P1  0                               // float[128]  loss partials
#define OFF_CP  (OFF_P1 + NBLK*4)               // u32[128]
#define OFF_CN  (OFF_CP + NBLK*4)               // u32[128]
#define OFF_PLB (OFF_CN + NBLK*4 + 4)           // pad to 16 -> float4[128*256]
#define OFF_PLA (OFF_PLB + NBLK*SEG*16)         // float[128*256]
#define OFF_NLB (OFF_PLA + NBLK*SEG*4)          // float4[128*256]
#define OFF_NLV (OFF_NLB + NBLK*SEG*16)         // float[128*256]
#define OFF_FLG (OFF_NLV + NBLK*SEG*4)          // u32[128*256]

__device__ __forceinline__ float sigmoidf_(float x) {
    return 1.0f / (1.0f + __expf(-x));
}

__global__ __launch_bounds__(256) void k1_elemwise(
    const float* __restrict__ pred, const float* __restrict__ gt,
    const float* __restrict__ anch, const int* __restrict__ epoch_p,
    char* __restrict__ ws)
{
    float*    partial1 = (float*)(ws + OFF_P1);
    unsigned* cntP  = (unsigned*)(ws + OFF_CP);
    unsigned* cntN  = (unsigned*)(ws + OFF_CN);
    float4*   plbox = (float4*)(ws + OFF_PLB);
    float*    plab  = (float*) (ws + OFF_PLA);
    float4*   nlbox = (float4*)(ws + OFF_NLB);
    float*    nlval = (float*) (ws + OFF_NLV);
    unsigned* flags = (unsigned*)(ws + OFF_FLG);

    __shared__ __align__(16) float sp[256*25];   // 25.6 KB
    __shared__ __align__(16) float sg[256*25];   // 25.6 KB
    __shared__ float red[4];
    __shared__ int wpo[4], wno[4];

    const int tid  = threadIdx.x;
    const int lane = tid & 63, wid = tid >> 6;
    const int b    = blockIdx.y;
    const int ch   = blockIdx.x;
    const int blin = b * CHK + ch;

    flags[blin*SEG + tid] = 0u;                  // zero all flag slots

    int n0   = ch * 256;
    int rows = min(256, N_ - n0);
    int ndw  = rows * 25;
    const float* srcP = pred + ((size_t)b*N_ + n0)*25;
    const float* srcG = gt   + ((size_t)b*N_ + n0)*25;
    for (int d = tid; d < ndw; d += 256) { sp[d] = srcP[d]; sg[d] = srcG[d]; }
    __syncthreads();

    int n = n0 + tid;
    bool valid = tid < rows;
    const float* P = sp + tid*25;
    const float* T = sg + tid*25;
    float local = 0.f;

    bool pos = false;
    float gx1=0, gy1=0, gx2=0, gy2=0, area_g=0;
    float px1=0, py1=0, px2=0, py2=0, pconf=0;

    if (valid) {
        int a  = n % A_;
        int g2 = (n / A_) % G_;
        int g1 = n / (A_ * G_);
        float px = P[0], py = P[1], pw = P[2], ph = P[3], po = P[4];
        float gx = T[0], gy = T[1], gw = T[2], gh = T[3], go = T[4];
        float aw = anch[a*2+0], ah = anch[a*2+1];

        float sx  = sigmoidf_(px), sy = sigmoidf_(py);
        float pbw = __expf(pw) * aw, pbh = __expf(ph) * ah;
        float gbw = __expf(gw) * aw, gbh = __expf(gh) * ah;

        float cxp = sx + (float)g2, cyp = sy + (float)g1;
        float hwp = pbw * (0.5f * G_), hhp = pbh * (0.5f * G_);
        px1 = cxp - hwp; py1 = cyp - hhp; px2 = cxp + hwp; py2 = cyp + hhp;

        float cxg = gx + (float)g2, cyg = gy + (float)g1;
        float hwg = gbw * (0.5f * G_), hhg = gbh * (0.5f * G_);
        gx1 = cxg - hwg; gy1 = cyg - hhg; gx2 = cxg + hwg; gy2 = cyg + hhg;

        pconf = sigmoidf_(po);
        float area_p = fmaxf(px2 - px1, 0.f) * fmaxf(py2 - py1, 0.f);
        area_g = fmaxf(gx2 - gx1, 0.f) * fmaxf(gy2 - gy1, 0.f);

        if (*epoch_p < 12) {
            local += 0.01f * (px*px + py*py + pw*pw + ph*ph);
        }
        pos = go > 0.5f;
        if (pos) {
            float d0 = gx - sx, d1 = gy - sy, d2 = gw - pw, d3 = gh - ph;
            local += 5.0f * (d0*d0 + d1*d1 + d2*d2 + d3*d3);
            float ix1 = fmaxf(px1, gx1), iy1 = fmaxf(py1, gy1);
            float ix2 = fminf(px2, gx2), iy2 = fminf(py2, gy2);
            float iw = fmaxf(ix2 - ix1, 0.f), ih = fmaxf(iy2 - iy1, 0.f);
            float inter = iw * ih;
            float iou = inter / (area_p + area_g - inter + EPSF);
            float dc = iou - pconf;
            local += dc * dc;
            float cl[C_];
            float m = -1e30f;
            #pragma unroll
            for (int c = 0; c < C_; c++) { cl[c] = P[5+c]; m = fmaxf(m, cl[c]); }
            float s = 0.f;
            #pragma unroll
            for (int c = 0; c < C_; c++) { cl[c] = __expf(cl[c] - m); s += cl[c]; }
            float inv = 1.0f / s;
            float acc = 0.f;
            #pragma unroll
            for (int c = 0; c < C_; c++) { float d = T[5+c] - cl[c]*inv; acc += d*d; }
            local += acc;
        }
        local *= (1.0f / BS_);
    }

    // deterministic block-local compaction into this block's segment
    bool isPos = valid && pos;
    bool isNeg = valid && !pos;
    unsigned long long mp = __ballot(isPos);
    unsigned long long mn = __ballot(isNeg);
    unsigned long long ltm = (1ull << lane) - 1ull;
    int ppre = __popcll(mp & ltm);
    int npre = __popcll(mn & ltm);
    if (lane == 0) { wpo[wid] = __popcll(mp); wno[wid] = __popcll(mn); }
    __syncthreads();
    int pexc = 0, nexc = 0, tp = 0, tn = 0;
    #pragma unroll
    for (int w = 0; w < 4; w++) {
        if (w < wid) { pexc += wpo[w]; nexc += wno[w]; }
        tp += wpo[w]; tn += wno[w];
    }
    if (isPos) {
        int k = blin*SEG + pexc + ppre;
        plbox[k] = make_float4(gx1, gy1, gx2, gy2);
        plab[k]  = area_g;
    } else if (isNeg) {
        int k = blin*SEG + nexc + npre;
        nlbox[k] = make_float4(px1, py1, px2, py2);
        nlval[k] = (0.5f / BS_) * pconf * pconf;
    }
    if (tid == 0) { cntP[blin] = (unsigned)tp; cntN[blin] = (unsigned)tn; }

    // block loss partial
    for (int off = 32; off; off >>= 1) local += __shfl_down(local, off);
    if (lane == 0) red[wid] = local;
    __syncthreads();
    if (tid == 0) partial1[blin] = red[0] + red[1] + red[2] + red[3];
}

__global__ __launch_bounds__(256) void k2_pairmax(char* __restrict__ ws)
{
    const unsigned* cntP  = (const unsigned*)(ws + OFF_CP);
    const unsigned* cntN  = (const unsigned*)(ws + OFF_CN);
    const float4*   plbox = (const float4*)(ws + OFF_PLB);
    const float*    plab  = (const float*) (ws + OFF_PLA);
    const float4*   nlbox = (const float4*)(ws + OFF_NLB);
    unsigned*       flags = (unsigned*)(ws + OFF_FLG);

    const int jc = blockIdx.x;          // 0..7  (pos segment)
    const int ip = blockIdx.y;          // 0..3  (pair of neg segments)
    const int b  = blockIdx.z;
    const int tid = threadIdx.x;

    const int jblin = b*CHK + jc;
    const int iblin0 = b*CHK + ip*2;
    const int iblin1 = iblin0 + 1;

    int jlen = (int)cntP[jblin];
    if (jlen <= 0) return;              // uniform

    __shared__ float4 sbox[SEG];
    __shared__ float  sb06[SEG];
    if (tid < jlen) {
        sbox[tid] = plbox[jblin*SEG + tid];
        sb06[tid] = -0.6f * plab[jblin*SEG + tid];
    }
    __syncthreads();

    int n0 = (int)cntN[iblin0], n1 = (int)cntN[iblin1];
    bool v0 = tid < n0, v1 = tid < n1;
    float4 p0 = v0 ? nlbox[iblin0*SEG + tid] : make_float4(0,0,0,0);
    float4 p1 = v1 ? nlbox[iblin1*SEG + tid] : make_float4(0,0,0,0);
    float c0 = (p0.z - p0.x) * (p0.w - p0.y) + EPSF;
    float c1 = (p1.z - p1.x) * (p1.w - p1.y) + EPSF;

    float md0 = -1e30f, md1 = -1e30f;
    for (int j = 0; j < jlen; j++) {
        float4 g = sbox[j];
        float tt = sb06[j];
        float ax0 = fmaxf(p0.x, g.x), ay0 = fmaxf(p0.y, g.y);
        float bx0 = fminf(p0.z, g.z), by0 = fminf(p0.w, g.w);
        float in0 = fmaxf(bx0 - ax0, 0.f) * fmaxf(by0 - ay0, 0.f);
        md0 = fmaxf(md0, fmaf(1.6f, in0, tt));      // 1.6*inter - 0.6*area_b
        float ax1 = fmaxf(p1.x, g.x), ay1 = fmaxf(p1.y, g.y);
        float bx1 = fminf(p1.z, g.z), by1 = fminf(p1.w, g.w);
        float in1 = fmaxf(bx1 - ax1, 0.f) * fmaxf(by1 - ay1, 0.f);
        md1 = fmaxf(md1, fmaf(1.6f, in1, tt));
    }
    // iou >= 0.6  <=>  1.6*inter - 0.6*area_b >= 0.6*(area_a + eps)
    if (v0 && md0 >= 0.6f * c0) flags[iblin0*SEG + tid] = 1u;  // same-value race: benign
    if (v1 && md1 >= 0.6f * c1) flags[iblin1*SEG + tid] = 1u;
}

__global__ __launch_bounds__(1024) void k3_final(char* __restrict__ ws,
                                                 float* __restrict__ out)
{
    const float*    partial1 = (const float*)(ws + OFF_P1);
    const unsigned* cntN  = (const unsigned*)(ws + OFF_CN);
    const float*    nlval = (const float*) (ws + OFF_NLV);
    const unsigned* flags = (const unsigned*)(ws + OFF_FLG);

    const int tid = threadIdx.x;
    float v = 0.f;
    for (int e = tid; e < NBLK*SEG; e += 1024) {
        int blin = e >> 8, k = e & 255;
        if (k < (int)cntN[blin] && flags[e] == 0u) v += nlval[e];
    }
    if (tid < NBLK) v += partial1[tid];

    for (int off = 32; off; off >>= 1) v += __shfl_down(v, off);
    __shared__ float red[16];
    int wid = tid >> 6, lane = tid & 63;
    if (lane == 0) red[wid] = v;
    __syncthreads();
    if (tid == 0) {
        float s = 0.f;
        #pragma unroll
        for (int w = 0; w < 16; w++) s += red[w];
        out[0] = s;
    }
}

extern "C" void kernel_launch(void* const* d_in, const int* in_sizes, int n_in,
                              void* d_out, int out_size, void* d_ws, size_t ws_size,
                              hipStream_t stream) {
    const float* pred  = (const float*)d_in[0];
    const float* gt_   = (const float*)d_in[1];
    const float* anch  = (const float*)d_in[2];
    const int*   epoch = (const int*)d_in[3];
    float* out = (float*)d_out;
    char*  ws  = (char*)d_ws;

    dim3 g1(CHK, BS_);
    k1_elemwise<<<g1, 256, 0, stream>>>(pred, gt_, anch, epoch, ws);
    dim3 g2(CHK, CHK/2, BS_);
    k2_pairmax<<<g2, 256, 0, stream>>>(ws);
    k3_final<<<1, 1024, 0, stream>>>(ws, out);
}

// Round 6
// 28.501 us; speedup vs baseline: 3.7629x; 1.7787x over previous
//
#include <hip/hip_runtime.h>

#define G_ 19
#define A_ 5
#define C_ 20
#define BS_ 16
#define N_ (G_*G_*A_)        // 1805
#define CHK 8                // segments (blocks) per batch
#define SEG 256              // slots per segment
#define NBLK (BS_*CHK)       // 128
#define EPSF 1e-8f

// ws byte offsets (16B-aligned blocks)
#define OFF_P1  0                               // float[128]  loss partials
#define OFF_CP  (OFF_P1 + NBLK*4)               // u32[128]
#define OFF_CN  (OFF_CP + NBLK*4)               // u32[128]
#define OFF_PLB (OFF_CN + NBLK*4 + 4)           // pad to 16 -> float4[128*256]
#define OFF_PLA (OFF_PLB + NBLK*SEG*16)         // float[128*256]
#define OFF_NLB (OFF_PLA + NBLK*SEG*4)          // float4[128*256]
#define OFF_NLV (OFF_NLB + NBLK*SEG*16)         // float[128*256]
#define OFF_FLG (OFF_NLV + NBLK*SEG*4)          // u32[128*256]

__device__ __forceinline__ float sigmoidf_(float x) {
    return 1.0f / (1.0f + __expf(-x));
}

__global__ __launch_bounds__(256) void k1_elemwise(
    const float* __restrict__ pred, const float* __restrict__ gt,
    const float* __restrict__ anch, const int* __restrict__ epoch_p,
    char* __restrict__ ws, float* __restrict__ out)
{
    float*    partial1 = (float*)(ws + OFF_P1);
    unsigned* cntP  = (unsigned*)(ws + OFF_CP);
    unsigned* cntN  = (unsigned*)(ws + OFF_CN);
    float4*   plbox = (float4*)(ws + OFF_PLB);
    float*    plab  = (float*) (ws + OFF_PLA);
    float4*   nlbox = (float4*)(ws + OFF_NLB);
    float*    nlval = (float*) (ws + OFF_NLV);
    unsigned* flags = (unsigned*)(ws + OFF_FLG);

    __shared__ __align__(16) float sp[256*25];   // 25.6 KB
    __shared__ __align__(16) float sg[256*25];   // 25.6 KB
    __shared__ float red[4];
    __shared__ int wpo[4], wno[4];

    const int tid  = threadIdx.x;
    const int lane = tid & 63, wid = tid >> 6;
    const int b    = blockIdx.y;
    const int ch   = blockIdx.x;
    const int blin = b * CHK + ch;

    flags[blin*SEG + tid] = 0u;                  // zero all flag slots
    if (blin == 0 && tid == 0) out[0] = 0.f;     // safe: k3's atomics are stream-ordered after k1

    int n0   = ch * 256;
    int rows = min(256, N_ - n0);
    int ndw  = rows * 25;
    const float* srcP = pred + ((size_t)b*N_ + n0)*25;
    const float* srcG = gt   + ((size_t)b*N_ + n0)*25;
    for (int d = tid; d < ndw; d += 256) { sp[d] = srcP[d]; sg[d] = srcG[d]; }
    __syncthreads();

    int n = n0 + tid;
    bool valid = tid < rows;
    const float* P = sp + tid*25;
    const float* T = sg + tid*25;
    float local = 0.f;

    bool pos = false;
    float gx1=0, gy1=0, gx2=0, gy2=0, area_g=0;
    float px1=0, py1=0, px2=0, py2=0, pconf=0;

    if (valid) {
        int a  = n % A_;
        int g2 = (n / A_) % G_;
        int g1 = n / (A_ * G_);
        float px = P[0], py = P[1], pw = P[2], ph = P[3], po = P[4];
        float gx = T[0], gy = T[1], gw = T[2], gh = T[3], go = T[4];
        float aw = anch[a*2+0], ah = anch[a*2+1];

        float sx  = sigmoidf_(px), sy = sigmoidf_(py);
        float pbw = __expf(pw) * aw, pbh = __expf(ph) * ah;
        float gbw = __expf(gw) * aw, gbh = __expf(gh) * ah;

        float cxp = sx + (float)g2, cyp = sy + (float)g1;
        float hwp = pbw * (0.5f * G_), hhp = pbh * (0.5f * G_);
        px1 = cxp - hwp; py1 = cyp - hhp; px2 = cxp + hwp; py2 = cyp + hhp;

        float cxg = gx + (float)g2, cyg = gy + (float)g1;
        float hwg = gbw * (0.5f * G_), hhg = gbh * (0.5f * G_);
        gx1 = cxg - hwg; gy1 = cyg - hhg; gx2 = cxg + hwg; gy2 = cyg + hhg;

        pconf = sigmoidf_(po);
        float area_p = fmaxf(px2 - px1, 0.f) * fmaxf(py2 - py1, 0.f);
        area_g = fmaxf(gx2 - gx1, 0.f) * fmaxf(gy2 - gy1, 0.f);

        if (*epoch_p < 12) {
            local += 0.01f * (px*px + py*py + pw*pw + ph*ph);
        }
        pos = go > 0.5f;
        if (pos) {
            float d0 = gx - sx, d1 = gy - sy, d2 = gw - pw, d3 = gh - ph;
            local += 5.0f * (d0*d0 + d1*d1 + d2*d2 + d3*d3);
            float ix1 = fmaxf(px1, gx1), iy1 = fmaxf(py1, gy1);
            float ix2 = fminf(px2, gx2), iy2 = fminf(py2, gy2);
            float iw = fmaxf(ix2 - ix1, 0.f), ih = fmaxf(iy2 - iy1, 0.f);
            float inter = iw * ih;
            float iou = inter / (area_p + area_g - inter + EPSF);
            float dc = iou - pconf;
            local += dc * dc;
            float cl[C_];
            float m = -1e30f;
            #pragma unroll
            for (int c = 0; c < C_; c++) { cl[c] = P[5+c]; m = fmaxf(m, cl[c]); }
            float s = 0.f;
            #pragma unroll
            for (int c = 0; c < C_; c++) { cl[c] = __expf(cl[c] - m); s += cl[c]; }
            float inv = 1.0f / s;
            float acc = 0.f;
            #pragma unroll
            for (int c = 0; c < C_; c++) { float d = T[5+c] - cl[c]*inv; acc += d*d; }
            local += acc;
        }
        local *= (1.0f / BS_);
    }

    // deterministic block-local compaction into this block's segment
    bool isPos = valid && pos;
    bool isNeg = valid && !pos;
    unsigned long long mp = __ballot(isPos);
    unsigned long long mn = __ballot(isNeg);
    unsigned long long ltm = (1ull << lane) - 1ull;
    int ppre = __popcll(mp & ltm);
    int npre = __popcll(mn & ltm);
    if (lane == 0) { wpo[wid] = __popcll(mp); wno[wid] = __popcll(mn); }
    __syncthreads();
    int pexc = 0, nexc = 0, tp = 0, tn = 0;
    #pragma unroll
    for (int w = 0; w < 4; w++) {
        if (w < wid) { pexc += wpo[w]; nexc += wno[w]; }
        tp += wpo[w]; tn += wno[w];
    }
    if (isPos) {
        int k = blin*SEG + pexc + ppre;
        plbox[k] = make_float4(gx1, gy1, gx2, gy2);
        plab[k]  = area_g;
    } else if (isNeg) {
        int k = blin*SEG + nexc + npre;
        nlbox[k] = make_float4(px1, py1, px2, py2);
        nlval[k] = (0.5f / BS_) * pconf * pconf;
    }
    if (tid == 0) { cntP[blin] = (unsigned)tp; cntN[blin] = (unsigned)tn; }

    // block loss partial
    for (int off = 32; off; off >>= 1) local += __shfl_down(local, off);
    if (lane == 0) red[wid] = local;
    __syncthreads();
    if (tid == 0) partial1[blin] = red[0] + red[1] + red[2] + red[3];
}

__global__ __launch_bounds__(256) void k2_pairmax(char* __restrict__ ws)
{
    const unsigned* cntP  = (const unsigned*)(ws + OFF_CP);
    const unsigned* cntN  = (const unsigned*)(ws + OFF_CN);
    const float4*   plbox = (const float4*)(ws + OFF_PLB);
    const float*    plab  = (const float*) (ws + OFF_PLA);
    const float4*   nlbox = (const float4*)(ws + OFF_NLB);
    unsigned*       flags = (unsigned*)(ws + OFF_FLG);

    const int jc = blockIdx.x;          // 0..7  (pos segment)
    const int ip = blockIdx.y;          // 0..3  (pair of neg segments)
    const int b  = blockIdx.z;
    const int tid = threadIdx.x;

    const int jblin = b*CHK + jc;
    const int iblin0 = b*CHK + ip*2;
    const int iblin1 = iblin0 + 1;

    int jlen = (int)cntP[jblin];
    if (jlen <= 0) return;              // uniform

    __shared__ float4 sbox[SEG];
    __shared__ float  sb06[SEG];
    if (tid < jlen) {
        sbox[tid] = plbox[jblin*SEG + tid];
        sb06[tid] = -0.6f * plab[jblin*SEG + tid];
    }
    __syncthreads();

    int n0 = (int)cntN[iblin0], n1 = (int)cntN[iblin1];
    bool v0 = tid < n0, v1 = tid < n1;
    float4 p0 = v0 ? nlbox[iblin0*SEG + tid] : make_float4(0,0,0,0);
    float4 p1 = v1 ? nlbox[iblin1*SEG + tid] : make_float4(0,0,0,0);
    float c0 = (p0.z - p0.x) * (p0.w - p0.y) + EPSF;
    float c1 = (p1.z - p1.x) * (p1.w - p1.y) + EPSF;

    float md0 = -1e30f, md1 = -1e30f;
    for (int j = 0; j < jlen; j++) {
        float4 g = sbox[j];
        float tt = sb06[j];
        float ax0 = fmaxf(p0.x, g.x), ay0 = fmaxf(p0.y, g.y);
        float bx0 = fminf(p0.z, g.z), by0 = fminf(p0.w, g.w);
        float in0 = fmaxf(bx0 - ax0, 0.f) * fmaxf(by0 - ay0, 0.f);
        md0 = fmaxf(md0, fmaf(1.6f, in0, tt));      // 1.6*inter - 0.6*area_b
        float ax1 = fmaxf(p1.x, g.x), ay1 = fmaxf(p1.y, g.y);
        float bx1 = fminf(p1.z, g.z), by1 = fminf(p1.w, g.w);
        float in1 = fmaxf(bx1 - ax1, 0.f) * fmaxf(by1 - ay1, 0.f);
        md1 = fmaxf(md1, fmaf(1.6f, in1, tt));
    }
    // iou >= 0.6  <=>  1.6*inter - 0.6*area_b >= 0.6*(area_a + eps)
    if (v0 && md0 >= 0.6f * c0) flags[iblin0*SEG + tid] = 1u;  // same-value race: benign
    if (v1 && md1 >= 0.6f * c1) flags[iblin1*SEG + tid] = 1u;
}

__global__ __launch_bounds__(256) void k3_final(char* __restrict__ ws,
                                                float* __restrict__ out)
{
    const float*    partial1 = (const float*)(ws + OFF_P1);
    const unsigned* cntN  = (const unsigned*)(ws + OFF_CN);
    const float*    nlval = (const float*) (ws + OFF_NLV);
    const unsigned* flags = (const unsigned*)(ws + OFF_FLG);

    const int tid  = threadIdx.x;
    const int blin = blockIdx.x;
    const int lane = tid & 63, wid = tid >> 6;

    float v = 0.f;
    if (tid < (int)cntN[blin] && flags[blin*SEG + tid] == 0u)
        v = nlval[blin*SEG + tid];
    if (tid == 0) v += partial1[blin];

    for (int off = 32; off; off >>= 1) v += __shfl_down(v, off);
    __shared__ float red[4];
    if (lane == 0) red[wid] = v;
    __syncthreads();
    if (tid == 0) atomicAdd(out, red[0] + red[1] + red[2] + red[3]);
}

extern "C" void kernel_launch(void* const* d_in, const int* in_sizes, int n_in,
                              void* d_out, int out_size, void* d_ws, size_t ws_size,
                              hipStream_t stream) {
    const float* pred  = (const float*)d_in[0];
    const float* gt_   = (const float*)d_in[1];
    const float* anch  = (const float*)d_in[2];
    const int*   epoch = (const int*)d_in[3];
    float* out = (float*)d_out;
    char*  ws  = (char*)d_ws;

    dim3 g1(CHK, BS_);
    k1_elemwise<<<g1, 256, 0, stream>>>(pred, gt_, anch, epoch, ws, out);
    dim3 g2(CHK, CHK/2, BS_);
    k2_pairmax<<<g2, 256, 0, stream>>>(ws);
    k3_final<<<NBLK, 256, 0, stream>>>(ws, out);
}